// Round 7
// baseline (466.476 us; speedup 1.0000x reference)
//
#include <hip/hip_runtime.h>
#include <stdint.h>

// Problem constants (B, T, V, E, U)
constexpr int NB = 1024;
constexpr int NT = 80;
constexpr int NV = 50000;
constexpr int NE = 512;
constexpr int NU = 512;

typedef __attribute__((ext_vector_type(8))) __bf16 bf16x8;
typedef __attribute__((ext_vector_type(4))) float f32x4;
typedef __attribute__((ext_vector_type(4))) uint16_t u16x4;
typedef __attribute__((ext_vector_type(4))) float float4v;
typedef __attribute__((ext_vector_type(4))) uint32_t u32x4;

__device__ __forceinline__ uint16_t f2bf(float f) {
  uint32_t u = __builtin_bit_cast(uint32_t, f);
  u += 0x7FFFu + ((u >> 16) & 1u);   // round-to-nearest-even
  return (uint16_t)(u >> 16);
}
__device__ __forceinline__ float bf2f(uint16_t h) {
  uint32_t u = ((uint32_t)h) << 16;
  return __builtin_bit_cast(float, u);
}
__device__ __forceinline__ float tanh_fast(float x) {
  float e = __expf(2.0f * x);
  return 1.0f - 2.0f / (e + 1.0f);
}

// LLC-coherent (device-scope) 16B load/store: sc0 sc1 bypass L1+L2 -> data
// serializes at the Infinity Cache coherence point; correct regardless of
// block->XCD placement. Explicit vmcnt waits required around these.
__device__ __forceinline__ void store16_cc(uint16_t* p, u32x4 v) {
  asm volatile("global_store_dwordx4 %0, %1, off sc0 sc1" :: "v"(p), "v"(v) : "memory");
}
__device__ __forceinline__ u32x4 load16_cc(const uint16_t* p) {
  u32x4 r;
  asm volatile("global_load_dwordx4 %0, %1, off sc0 sc1" : "=v"(r) : "v"(p) : "memory");
  return r;
}

// ---------------- prep kernels ----------------

__global__ __launch_bounds__(256) void emb_to_bf16(const float* __restrict__ in,
                                                   uint16_t* __restrict__ out) {
  int i = blockIdx.x * 256 + threadIdx.x;           // 6,400,000 float4s
  float4v v = ((const float4v*)in)[i];
  u16x4 o;
  o.x = f2bf(v.x); o.y = f2bf(v.y); o.z = f2bf(v.z); o.w = f2bf(v.w);
  ((u16x4*)out)[i] = o;
}

// Pack a [K=512][N=512] fp32 weight into MFMA-B-fragment order:
// pack[nt][ks][lane][j] = bf16( W[ks*32 + (lane>>4)*8 + j][nt*16 + (lane&15)] )
__global__ __launch_bounds__(256) void pack_w(const float* __restrict__ w,
                                              uint16_t* __restrict__ out) {
  int idx = blockIdx.x * 256 + threadIdx.x;  // 0..32767 = 32 nt * 16 ks * 64 lanes
  int lane = idx & 63;
  int ks = (idx >> 6) & 15;
  int nt = idx >> 10;
  int n  = nt * 16 + (lane & 15);
  int k0 = ks * 32 + (lane >> 4) * 8;
  uint16_t v[8];
#pragma unroll
  for (int j = 0; j < 8; j++) v[j] = f2bf(w[(size_t)(k0 + j) * NU + n]);
  u16x4* o = (u16x4*)(out + (size_t)idx * 8);
  o[0] = (u16x4){v[0], v[1], v[2], v[3]};
  o[1] = (u16x4){v[4], v[5], v[6], v[7]};
}

// ---------------- projection GEMM (round-3 version, best measured) -------
__global__ __launch_bounds__(256, 2) void proj_gemm(const int* __restrict__ tokens,
                                                    const uint16_t* __restrict__ embb,
                                                    const uint16_t* __restrict__ kpack,
                                                    const float* __restrict__ bias,
                                                    uint16_t* __restrict__ xkp) {
  int wave = threadIdx.x >> 6;
  int lane = threadIdx.x & 63;
  int ln15 = lane & 15;
  int quad = lane >> 4;
  int m0 = blockIdx.x * 64;      // 1280 blocks: 80 t x 16 b-groups
  int t = m0 >> 10;
  int b0 = m0 & 1023;

  int tok[4];
#pragma unroll
  for (int mt = 0; mt < 4; mt++)
    tok[mt] = tokens[(size_t)(b0 + mt * 16 + ln15) * NT + t];

  float bv[8];
#pragma unroll
  for (int nt = 0; nt < 8; nt++) bv[nt] = bias[wave * 128 + nt * 16 + ln15];

  f32x4 acc[4][8];
#pragma unroll
  for (int mt = 0; mt < 4; mt++)
#pragma unroll
    for (int nt = 0; nt < 8; nt++) acc[mt][nt] = (f32x4){0.f, 0.f, 0.f, 0.f};

  bf16x8 aC[4], aN[4];
#pragma unroll
  for (int mt = 0; mt < 4; mt++) {
    aC[mt] = *(const bf16x8*)(embb + (size_t)tok[mt] * NE + 0 * 32 + quad * 8);
    aN[mt] = *(const bf16x8*)(embb + (size_t)tok[mt] * NE + 1 * 32 + quad * 8);
  }

#pragma unroll 1
  for (int ks = 0; ks < 16; ks++) {
    bf16x8 aF[4];
    int ksn = (ks + 2) & 15;   // wraps harmlessly for ks=14,15
#pragma unroll
    for (int mt = 0; mt < 4; mt++)
      aF[mt] = *(const bf16x8*)(embb + (size_t)tok[mt] * NE + ksn * 32 + quad * 8);
#pragma unroll
    for (int nt = 0; nt < 8; nt++) {
      int ntg = wave * 8 + nt;
      bf16x8 bfr = *(const bf16x8*)(kpack + (((size_t)ntg * 16 + ks) * 64 + lane) * 8);
#pragma unroll
      for (int mt = 0; mt < 4; mt++)
        acc[mt][nt] = __builtin_amdgcn_mfma_f32_16x16x32_bf16(aC[mt], bfr, acc[mt][nt], 0, 0, 0);
    }
#pragma unroll
    for (int mt = 0; mt < 4; mt++) { aC[mt] = aN[mt]; aN[mt] = aF[mt]; }
  }

  // epilogue: C-fragment-order tiles, coalesced 8B/lane stores
#pragma unroll
  for (int mt = 0; mt < 4; mt++) {
    int g = (b0 >> 4) + mt;
#pragma unroll
    for (int nt = 0; nt < 8; nt++) {
      int ntg = wave * 8 + nt;
      size_t tile = ((size_t)t * 64 + g) * 32 + ntg;
      u16x4 o;
      o.x = f2bf(acc[mt][nt][0] + bv[nt]);
      o.y = f2bf(acc[mt][nt][1] + bv[nt]);
      o.z = f2bf(acc[mt][nt][2] + bv[nt]);
      o.w = f2bf(acc[mt][nt][3] + bv[nt]);
      *(u16x4*)(xkp + tile * 256 + (size_t)lane * 4) = o;
    }
  }
}

// ---------------- recurrence: 4-CU split, 1 barrier/step -----------------
// 256 blocks x 256 threads. Block (g=bid&63, s=bid>>6): rows g*16..+15,
// cols s*128..+127. Wave w owns n-tiles s*8+2w,+1 = cols (global) covering
// k-region = s*4+w (32 cols). B-frags 128 VGPR, pinned at 1 wave/SIMD.
// hS double-buffered [2][16 regions][512 u16], region = A-frag layout
// [row(16)][qw(4)][j(8)]. Per step, per wave:
//   compute -> tanh -> repack own 1KB region into hn (wave-internal)
//   -> ds_read own 16B -> sc1 store -> vmcnt -> per-REGION flag
//   -> prefetch xv(t+1) -> (waves 1-3) poll partner's 4 region-flags,
//      load 4KB chunk, linear LDS write -> ONE lgkm-only s_barrier.
__global__ __launch_bounds__(256, 1)
void rnn_rec(const uint16_t* __restrict__ xkp,
             const uint16_t* __restrict__ rpack,
             const float* __restrict__ fcw,
             const float* __restrict__ fcb,
             uint16_t* __restrict__ hx,    // [2][64][16][512] u16
             int* __restrict__ flags,      // [64][16]
             float* __restrict__ out) {
  __shared__ uint16_t hS[2][16 * 512];   // 2 x 16 KB

  const int bid = blockIdx.x;
  const int g = bid & 63, s = bid >> 6;
  const int wave = threadIdx.x >> 6, lane = threadIdx.x & 63;
  const int ln15 = lane & 15, quad = lane >> 4;
  const int ntg0 = s * 8 + wave * 2;
  const int region = s * 4 + wave;        // k-region this wave produces

  // B-frags: 2 nt x 16 ks = 128 VGPRs, loaded once and pinned (budget 512)
  bf16x8 bf0[16], bf1[16];
#pragma unroll
  for (int ks = 0; ks < 16; ks++) {
    bf0[ks] = *(const bf16x8*)(rpack + (((size_t)(ntg0 + 0) * 16 + ks) * 64 + lane) * 8);
    bf1[ks] = *(const bf16x8*)(rpack + (((size_t)(ntg0 + 1) * 16 + ks) * 64 + lane) * 8);
    asm volatile("" : "+v"(bf0[ks]));
    asm volatile("" : "+v"(bf1[ks]));
  }

  // h(0) = 0 in buffer 0
  {
    u32x4 z = (u32x4){0u, 0u, 0u, 0u};
#pragma unroll
    for (int i = 0; i < 4; i++) ((u32x4*)hS[0])[i * 256 + threadIdx.x] = z;
  }
  __syncthreads();

  // prefetch xv(0)
  u16x4 xv0 = *(const u16x4*)(xkp + ((size_t)(0 * 64 + g) * 32 + ntg0 + 0) * 256 + (size_t)lane * 4);
  u16x4 xv1 = *(const u16x4*)(xkp + ((size_t)(0 * 64 + g) * 32 + ntg0 + 1) * 256 + (size_t)lane * 4);

  for (int t = 0; t < NT; t++) {
    const uint16_t* hc = hS[t & 1];
    uint16_t* hn = hS[(t + 1) & 1];
    const int par = (t + 1) & 1;

    // compute: A from LDS, B from pinned regs; split chains (2x8 deep)
    f32x4 a0a = (f32x4){0.f, 0.f, 0.f, 0.f}, a0b = a0a, a1a = a0a, a1b = a0a;
#pragma unroll
    for (int ks = 0; ks < 8; ks++) {
      bf16x8 a = *(const bf16x8*)(hc + (size_t)ks * 512 + ln15 * 32 + quad * 8);
      a0a = __builtin_amdgcn_mfma_f32_16x16x32_bf16(a, bf0[ks], a0a, 0, 0, 0);
      a1a = __builtin_amdgcn_mfma_f32_16x16x32_bf16(a, bf1[ks], a1a, 0, 0, 0);
    }
#pragma unroll
    for (int ks = 8; ks < 16; ks++) {
      bf16x8 a = *(const bf16x8*)(hc + (size_t)ks * 512 + ln15 * 32 + quad * 8);
      a0b = __builtin_amdgcn_mfma_f32_16x16x32_bf16(a, bf0[ks], a0b, 0, 0, 0);
      a1b = __builtin_amdgcn_mfma_f32_16x16x32_bf16(a, bf1[ks], a1b, 0, 0, 0);
    }
    f32x4 acc0 = a0a + a0b, acc1 = a1a + a1b;

    // tanh
    uint16_t hv0[4], hv1[4];
#pragma unroll
    for (int r = 0; r < 4; r++) {
      hv0[r] = f2bf(tanh_fast(acc0[r] + bf2f(xv0[r])));
      hv1[r] = f2bf(tanh_fast(acc1[r] + bf2f(xv1[r])));
    }

    // repack own 1KB region into hn (only THIS wave's lanes write it)
    {
      int j = ln15 & 7;
      int qw0 = (ln15 >> 3);        // ntl=0 -> qw 0..1
      int qw1 = 2 + (ln15 >> 3);    // ntl=1 -> qw 2..3
      uint16_t* rg = hn + (size_t)region * 512;
#pragma unroll
      for (int r = 0; r < 4; r++) {
        int row = quad * 4 + r;
        rg[row * 32 + qw0 * 8 + j] = hv0[r];
        rg[row * 32 + qw1 * 8 + j] = hv1[r];
      }
    }
    // wave-internal LDS ordering, then copy-out own 16B/lane (coalesced 1KB)
    u32x4 d = *(const u32x4*)(hn + (size_t)region * 512 + (size_t)lane * 8);
    store16_cc(hx + (((size_t)par * 64 + g) * 16 + region) * 512 + (size_t)lane * 8, d);
    asm volatile("s_waitcnt vmcnt(0)" ::: "memory");
    if (lane == 0)
      __hip_atomic_store(flags + g * 16 + region, t + 1, __ATOMIC_RELAXED,
                         __HIP_MEMORY_SCOPE_AGENT);

    // prefetch xv(t+1) (left in flight across the exchange)
    {
      int tn = (t + 1 < NT) ? t + 1 : t;
      xv0 = *(const u16x4*)(xkp + ((size_t)(tn * 64 + g) * 32 + ntg0 + 0) * 256 + (size_t)lane * 4);
      xv1 = *(const u16x4*)(xkp + ((size_t)(tn * 64 + g) * 32 + ntg0 + 1) * 256 + (size_t)lane * 4);
    }

    // staging: wave w in {1,2,3} fetches slice sp = (s+w)&3 (4 regions)
    if (wave > 0) {
      int sp = (s + wave) & 3;
      const int* fp = flags + g * 16 + sp * 4;
      int spin = 0;
      while (spin < (1 << 16)) {
        int f0 = __hip_atomic_load(fp + 0, __ATOMIC_RELAXED, __HIP_MEMORY_SCOPE_AGENT);
        int f1 = __hip_atomic_load(fp + 1, __ATOMIC_RELAXED, __HIP_MEMORY_SCOPE_AGENT);
        int f2 = __hip_atomic_load(fp + 2, __ATOMIC_RELAXED, __HIP_MEMORY_SCOPE_AGENT);
        int f3 = __hip_atomic_load(fp + 3, __ATOMIC_RELAXED, __HIP_MEMORY_SCOPE_AGENT);
        if (f0 >= t + 1 && f1 >= t + 1 && f2 >= t + 1 && f3 >= t + 1) break;
        spin++;
      }
      asm volatile("" ::: "memory");
      const uint16_t* src = hx + (((size_t)par * 64 + g) * 16 + sp * 4) * 512;
      u32x4 v[4];
#pragma unroll
      for (int i = 0; i < 4; i++) v[i] = load16_cc(src + (size_t)(i * 512) + (size_t)lane * 8);
      asm volatile("s_waitcnt vmcnt(0)" ::: "memory");
#pragma unroll
      for (int i = 0; i < 4; i++)
        *(u32x4*)(hn + (size_t)(sp * 4 + i) * 512 + (size_t)lane * 8) = v[i];
    }

    // ONE barrier per step; LDS-only drain (xv prefetch stays in flight)
    asm volatile("s_waitcnt lgkmcnt(0)\n\ts_barrier" ::: "memory");
  }

  // final FC + sigmoid: hS[0] holds h(80); s==0 blocks write 16 outputs
  if (s == 0) {
#pragma unroll
    for (int rr = 0; rr < 4; rr++) {
      int row = wave * 4 + rr;
      // cols lane*8..+7: region = lane>>2, qw = lane&3 -> contiguous 16B
      const uint16_t* hr = hS[0] + (size_t)(lane >> 2) * 512 + row * 32 + (lane & 3) * 8;
      float p = 0.f;
#pragma unroll
      for (int j = 0; j < 8; j++) p += bf2f(hr[j]) * fcw[lane * 8 + j];
#pragma unroll
      for (int off = 32; off; off >>= 1) p += __shfl_down(p, off);
      if (lane == 0) {
        float logit = p + fcb[0];
        out[g * 16 + row] = 1.0f / (1.0f + __expf(-logit));
      }
    }
  }
}

// ---------------- launcher ----------------
extern "C" void kernel_launch(void* const* d_in, const int* in_sizes, int n_in,
                              void* d_out, int out_size, void* d_ws, size_t ws_size,
                              hipStream_t stream) {
  const int* tokens   = (const int*)d_in[0];
  const float* emb    = (const float*)d_in[1];
  const float* kernel_w = (const float*)d_in[2];
  const float* rec_w  = (const float*)d_in[3];
  const float* bias   = (const float*)d_in[4];
  const float* fcw    = (const float*)d_in[5];
  const float* fcb    = (const float*)d_in[6];
  float* out = (float*)d_out;

  // workspace: emb_bf16 51.2MB | kpack 0.5MB | rpack 0.5MB | xkp 83.9MB |
  //            hx 2MB | flags 4KB   (~138.1 MB)
  uint16_t* embb  = (uint16_t*)d_ws;
  uint16_t* kpack = embb + (size_t)NV * NE;
  uint16_t* rpack = kpack + (size_t)NE * NU;
  uint16_t* xkp   = rpack + (size_t)NU * NU;
  uint16_t* hx    = xkp + (size_t)NT * NB * NU;            // 1,048,576 u16
  int* flags      = (int*)(hx + (size_t)2 * 64 * 16 * 512);
  // flags poisoned 0xAA -> 0xAAAAAAAA < 1 as signed int: valid initial state.

  hipLaunchKernelGGL(emb_to_bf16, dim3(25000), dim3(256), 0, stream, emb, embb);
  hipLaunchKernelGGL(pack_w, dim3(128), dim3(256), 0, stream, kernel_w, kpack);
  hipLaunchKernelGGL(pack_w, dim3(128), dim3(256), 0, stream, rec_w, rpack);
  hipLaunchKernelGGL(proj_gemm, dim3(1280), dim3(256), 0, stream, tokens, embb, kpack, bias, xkp);
  hipLaunchKernelGGL(rnn_rec, dim3(256), dim3(256), 0, stream, xkp, rpack, fcw, fcb, hx, flags, out);
}